// Round 1
// baseline (2287.572 us; speedup 1.0000x reference)
//
#include <hip/hip_runtime.h>

#define CIN 64
#define OC 128
#define HW 112
#define HWHW (HW*HW)

// Baseline: direct conv. One block = (n, o, 4-row h-tile), 128 lanes over W
// (112 active). Weights for this o staged in LDS. Each thread computes 4
// outputs along H, register-reusing a 6-row x column per (c,kw):
// per c: 18 global loads, 9 LDS broadcast reads, 36 FMAs.
__global__ __launch_bounds__(128) void conv3x3_direct(
    const float* __restrict__ x, const float* __restrict__ wgt,
    const float* __restrict__ bias, float* __restrict__ out)
{
    __shared__ float sw[CIN * 9];

    const int tid = threadIdx.x;
    const int o  = blockIdx.y;
    const int n  = blockIdx.z;
    const int h0 = blockIdx.x * 4;

    // Stage this o's weights: 576 contiguous floats, coalesced.
    const float* wsrc = wgt + (size_t)o * CIN * 9;
    for (int i = tid; i < CIN * 9; i += 128) sw[i] = wsrc[i];
    __syncthreads();

    const int w = tid;                 // 0..127, active if w < 112
    const bool wactive = (w < HW);

    const float b = bias[o];
    float acc0 = b, acc1 = b, acc2 = b, acc3 = b;

    const float* xn = x + (size_t)n * CIN * HWHW;

    for (int c = 0; c < CIN; ++c) {
        const float* xc = xn + c * HWHW;
        const float* wc = &sw[c * 9];

        #pragma unroll
        for (int kw = 0; kw < 3; ++kw) {
            const int ww = w + kw - 1;
            const bool wok = wactive && (ww >= 0) && (ww < HW);

            float xv[6];
            #pragma unroll
            for (int r = 0; r < 6; ++r) {
                const int hh = h0 + r - 1;
                const bool ok = wok && (hh >= 0) && (hh < HW);
                xv[r] = ok ? xc[hh * HW + ww] : 0.0f;
            }

            const float wk0 = wc[kw];
            const float wk1 = wc[3 + kw];
            const float wk2 = wc[6 + kw];

            acc0 += xv[0] * wk0; acc0 += xv[1] * wk1; acc0 += xv[2] * wk2;
            acc1 += xv[1] * wk0; acc1 += xv[2] * wk1; acc1 += xv[3] * wk2;
            acc2 += xv[2] * wk0; acc2 += xv[3] * wk1; acc2 += xv[4] * wk2;
            acc3 += xv[3] * wk0; acc3 += xv[4] * wk1; acc3 += xv[5] * wk2;
        }
    }

    if (wactive) {
        float* op = out + (((size_t)n * OC + o) * HW + h0) * HW + w;
        op[0 * HW] = acc0;
        op[1 * HW] = acc1;
        op[2 * HW] = acc2;
        op[3 * HW] = acc3;
    }
}

extern "C" void kernel_launch(void* const* d_in, const int* in_sizes, int n_in,
                              void* d_out, int out_size, void* d_ws, size_t ws_size,
                              hipStream_t stream) {
    const float* x    = (const float*)d_in[0];
    const float* wgt  = (const float*)d_in[1];
    const float* bias = (const float*)d_in[2];
    float* out = (float*)d_out;

    dim3 grid(HW / 4, OC, 32);   // (28 h-tiles, 128 o, 32 n)
    dim3 block(128);
    hipLaunchKernelGGL(conv3x3_direct, grid, block, 0, stream, x, wgt, bias, out);
}

// Round 2
// 483.415 us; speedup vs baseline: 4.7321x; 4.7321x over previous
//
#include <hip/hip_runtime.h>

#define CIN 64
#define OC 128
#define HW 112
#define HWHW (HW*HW)          // 12544
#define NIMG 32
#define M_TOTAL (NIMG*HWHW)   // 401408

// ws layout (bytes):
//   [0, XN_BYTES): x_nhwc bf16  [32][112][112][64]
//   [XN_BYTES, +256): zero page
//   [WT_OFF, +147456): wT bf16  [9][128][64]
#define XN_ELEMS (NIMG*HWHW*CIN)        // 25,690,112
#define XN_BYTES (XN_ELEMS*2)           // 51,380,224
#define ZERO_EL  XN_ELEMS               // element index of zero page
#define WT_OFF_EL (XN_ELEMS + 128)      // wT start, element index (16B aligned)

typedef __attribute__((ext_vector_type(8))) short short8;
typedef __attribute__((ext_vector_type(4))) float floatx4;

__device__ inline unsigned short f2bf(float f) {
    unsigned u = __float_as_uint(f);
    u += 0x7fffu + ((u >> 16) & 1u);   // RNE
    return (unsigned short)(u >> 16);
}

// ---- Kernel 1: x NCHW fp32 -> NHWC bf16 (LDS tile transpose), per (n,h) ----
__global__ __launch_bounds__(256) void xform_x(const float* __restrict__ x,
                                               unsigned short* __restrict__ xws)
{
    __shared__ float s[HW * (CIN + 1)];   // [w][c], pad to 65
    const int tid = threadIdx.x;
    const int n = blockIdx.x / HW;
    const int h = blockIdx.x % HW;

    const float* xp = x + (size_t)n * CIN * HWHW + h * HW;  // + c*HWHW + w
    for (int idx = tid; idx < CIN * HW; idx += 256) {
        int c = idx / HW;
        int w = idx - c * HW;
        s[w * (CIN + 1) + c] = xp[c * HWHW + w];
    }
    __syncthreads();

    unsigned short* op = xws + ((size_t)(n * HW + h)) * HW * CIN;  // [w][c]
    for (int idx = tid; idx < (CIN * HW) / 8; idx += 256) {        // 896
        int w  = idx >> 3;
        int c0 = (idx & 7) * 8;
        union { unsigned short us[8]; uint4 v; } u;
        #pragma unroll
        for (int j = 0; j < 8; ++j)
            u.us[j] = f2bf(s[w * (CIN + 1) + c0 + j]);
        *(uint4*)(op + w * CIN + c0) = u.v;
    }
}

// ---- Kernel 1b: weights [O][C][3][3] fp32 -> wT [tap][O][C] bf16 + zero page ----
__global__ __launch_bounds__(256) void xform_w(const float* __restrict__ wgt,
                                               unsigned short* __restrict__ ws16)
{
    const int idx = blockIdx.x * 256 + threadIdx.x;    // 0..73727
    const int c  = idx & 63;
    const int to = idx >> 6;
    const int o  = to & 127;
    const int t  = to >> 7;                            // 0..8
    ws16[WT_OFF_EL + idx] = f2bf(wgt[(o * CIN + c) * 9 + t]);
    if (blockIdx.x == 0 && threadIdx.x < 128)
        ws16[ZERO_EL + threadIdx.x] = 0;
}

// ---- Kernel 2: implicit-GEMM MFMA. Block=256thr=4 waves, tile 128m x 128o.
// Wave tile 64m x 64o: acc[4 mt][4 ot] of 16x16. A=weights (r=o), B=x (c=m).
__global__ __launch_bounds__(256) void conv_mfma(
    const unsigned short* __restrict__ ws16,
    const float* __restrict__ bias,
    float* __restrict__ out)
{
    const int tid = threadIdx.x;
    const int wave = tid >> 6;
    const int lane = tid & 63;
    const int lane_lo = lane & 15;
    const int lane_hi = lane >> 4;

    const int bm  = blockIdx.x;          // 0..3135
    const int n   = bm / 98;
    const int hw0 = (bm % 98) * 128;
    const int o0     = (wave & 1) * 64;
    const int m_half = (wave >> 1) * 64;

    // Per-lane (h,w) for each of the 4 m-tiles
    int h_[4], w_[4];
    #pragma unroll
    for (int mt = 0; mt < 4; ++mt) {
        unsigned hw = (unsigned)(hw0 + m_half + mt * 16 + lane_lo);
        unsigned h = hw / 112u;
        h_[mt] = (int)h;
        w_[mt] = (int)(hw - h * 112u);
    }

    floatx4 acc[4][4];
    #pragma unroll
    for (int mt = 0; mt < 4; ++mt)
        #pragma unroll
        for (int ot = 0; ot < 4; ++ot)
            acc[mt][ot] = (floatx4){0.f, 0.f, 0.f, 0.f};

    // A-frag element offsets (weights), per ot; tap adds 128*64 elems
    int a_el[4];
    #pragma unroll
    for (int ot = 0; ot < 4; ++ot)
        a_el[ot] = WT_OFF_EL + (o0 + ot * 16 + lane_lo) * CIN + lane_hi * 8;

    const int nbase = n * HWHW;

    for (int tap = 0; tap < 9; ++tap) {
        const int dh = tap / 3 - 1;
        const int dw = tap % 3 - 1;

        int boff[4];
        #pragma unroll
        for (int mt = 0; mt < 4; ++mt) {
            int hh = h_[mt] + dh;
            int ww = w_[mt] + dw;
            bool ok = ((unsigned)hh < 112u) & ((unsigned)ww < 112u);
            int el = ((nbase + hh * HW + ww) << 6) + (lane_hi << 3);
            boff[mt] = ok ? el : ZERO_EL;
        }

        const int wtap = tap * (OC * CIN);
        #pragma unroll
        for (int k0 = 0; k0 < CIN; k0 += 32) {
            short8 a[4], b[4];
            #pragma unroll
            for (int ot = 0; ot < 4; ++ot)
                a[ot] = *(const short8*)(ws16 + wtap + a_el[ot] + k0);
            #pragma unroll
            for (int mt = 0; mt < 4; ++mt)
                b[mt] = *(const short8*)(ws16 + boff[mt] + k0);
            #pragma unroll
            for (int mt = 0; mt < 4; ++mt)
                #pragma unroll
                for (int ot = 0; ot < 4; ++ot)
                    acc[mt][ot] = __builtin_amdgcn_mfma_f32_16x16x32_bf16(
                        a[ot], b[mt], acc[mt][ot], 0, 0, 0);
        }
    }

    // Epilogue: D row = o_rel = lane_hi*4+i, col = m_rel = lane_lo
    #pragma unroll
    for (int ot = 0; ot < 4; ++ot) {
        const int ob = o0 + ot * 16 + lane_hi * 4;
        const float4 bv = *(const float4*)(bias + ob);
        #pragma unroll
        for (int mt = 0; mt < 4; ++mt) {
            const int hw = hw0 + m_half + mt * 16 + lane_lo;
            float* op = out + (size_t)(n * OC + ob) * HWHW + hw;
            op[0]         = acc[mt][ot].x + bv.x;
            op[HWHW]      = acc[mt][ot].y + bv.y;
            op[2 * HWHW]  = acc[mt][ot].z + bv.z;
            op[3 * HWHW]  = acc[mt][ot].w + bv.w;
        }
    }
}

extern "C" void kernel_launch(void* const* d_in, const int* in_sizes, int n_in,
                              void* d_out, int out_size, void* d_ws, size_t ws_size,
                              hipStream_t stream) {
    const float* x    = (const float*)d_in[0];
    const float* wgt  = (const float*)d_in[1];
    const float* bias = (const float*)d_in[2];
    float* out = (float*)d_out;
    unsigned short* ws16 = (unsigned short*)d_ws;

    hipLaunchKernelGGL(xform_x, dim3(NIMG * HW), dim3(256), 0, stream, x, ws16);
    hipLaunchKernelGGL(xform_w, dim3(288), dim3(256), 0, stream, wgt, ws16);
    hipLaunchKernelGGL(conv_mfma, dim3(M_TOTAL / 128), dim3(256), 0, stream,
                       ws16, bias, out);
}

// Round 3
// 332.295 us; speedup vs baseline: 6.8842x; 1.4548x over previous
//
#include <hip/hip_runtime.h>

#define CIN 64
#define OC 128
#define HW 112
#define HWHW (HW*HW)          // 12544
#define NIMG 32

// ws layout (elems of bf16/ushort):
//   [0, XN_ELEMS): x_nhwc bf16  [32][112][112][64]
//   [WT_OFF_EL, +73728): weights bf16, layout [tap][k-half][128 o][32 c]
#define XN_ELEMS (NIMG*HWHW*CIN)        // 25,690,112
#define WT_OFF_EL (XN_ELEMS + 128)

#define ROWE (114*64)                   // LDS row slot: 114 cols (±1 pad) x 64c

typedef __attribute__((ext_vector_type(8))) short short8;
typedef __attribute__((ext_vector_type(4))) float floatx4;

__device__ inline unsigned short f2bf(float f) {
    unsigned u = __float_as_uint(f);
    u += 0x7fffu + ((u >> 16) & 1u);   // RNE
    return (unsigned short)(u >> 16);
}

__device__ inline void async16(const unsigned short* g, unsigned short* l) {
    __builtin_amdgcn_global_load_lds(
        (const __attribute__((address_space(1))) void*)g,
        (__attribute__((address_space(3))) void*)l, 16, 0, 0);
}

// ---- Kernel 1: x NCHW fp32 -> NHWC bf16 (LDS tile transpose), per (n,h) ----
__global__ __launch_bounds__(256) void xform_x(const float* __restrict__ x,
                                               unsigned short* __restrict__ xws)
{
    __shared__ float s[HW * (CIN + 1)];
    const int tid = threadIdx.x;
    const int n = blockIdx.x / HW;
    const int h = blockIdx.x % HW;

    const float* xp = x + (size_t)n * CIN * HWHW + h * HW;
    for (int idx = tid; idx < CIN * HW; idx += 256) {
        int c = idx / HW;
        int w = idx - c * HW;
        s[w * (CIN + 1) + c] = xp[c * HWHW + w];
    }
    __syncthreads();

    unsigned short* op = xws + ((size_t)(n * HW + h)) * HW * CIN;
    for (int idx = tid; idx < (CIN * HW) / 8; idx += 256) {
        int w  = idx >> 3;
        int c0 = (idx & 7) * 8;
        union { unsigned short us[8]; uint4 v; } u;
        #pragma unroll
        for (int j = 0; j < 8; ++j)
            u.us[j] = f2bf(s[w * (CIN + 1) + c0 + j]);
        *(uint4*)(op + w * CIN + c0) = u.v;
    }
}

// ---- Kernel 1b: weights [O][C][3][3] fp32 -> [tap][c>>5][o][c&31] bf16 ----
__global__ __launch_bounds__(256) void xform_w(const float* __restrict__ wgt,
                                               unsigned short* __restrict__ ws16)
{
    const int idx = blockIdx.x * 256 + threadIdx.x;    // 0..73727
    const int c = idx & 63;
    const int o = (idx >> 6) & 127;
    const int t = idx >> 13;                           // 0..8
    const float v = wgt[(o * CIN + c) * 9 + t];
    ws16[WT_OFF_EL + ((size_t)(t * 2 + (c >> 5)) * 128 + o) * 32 + (c & 31)] = f2bf(v);
}

// ---- Kernel 2: implicit-GEMM MFMA, x operand fully LDS-resident ----
// Block: 256 thr = 4 waves; tile 224m(2 rows) x 128o. Wave: 112m x 64o,
// MT=7, OT=4, acc[7][4] (112 AGPR). LDS: 4 x-row slots (h0-1..h0+2),
// 114 cols (pad) x 64c, XOR-swizzled c-blocks. One barrier total.
__global__ __launch_bounds__(256, 2) void conv_mfma(
    const unsigned short* __restrict__ ws16,
    const float* __restrict__ bias,
    float* __restrict__ out)
{
    __shared__ unsigned short sx[4 * ROWE];   // 58368 B

    const int tid  = threadIdx.x;
    const int wave = tid >> 6;
    const int lane = tid & 63;
    const int lane_lo = lane & 15;
    const int lane_hi = lane >> 4;

    const int bid = blockIdx.x;        // 0..1791
    const int n   = bid / 56;
    const int rp  = bid % 56;
    const int h0  = rp * 2;

    // ---- stage: wave s fills row slot s with image row h0+s-1 (or zeros) ----
    {
        const int slot = wave;
        const int hr = h0 + slot - 1;
        unsigned short* rowb = sx + slot * ROWE;
        if ((unsigned)hr < (unsigned)HW) {
            // zero the two pad columns (stored cols 0 and 113)
            if (lane < 8)        *(uint4*)(rowb + lane * 8) = (uint4){0,0,0,0};
            else if (lane < 16)  *(uint4*)(rowb + 113*64 + (lane - 8) * 8) = (uint4){0,0,0,0};
            const unsigned short* gr = ws16 + ((size_t)(n * HW + hr)) * HW * CIN;
            const int grp = lane >> 3;           // col within chunk
            const int sub = lane & 7;            // c-block slot
            // stored col ws = 1+j*8+grp -> ws&7 = (1+grp)&7; slot `sub` holds
            // logical c-block sub ^ (ws&7)
            const int swz = sub ^ ((1 + grp) & 7);
            const unsigned short* gl = gr + grp * 64 + swz * 8;
            #pragma unroll
            for (int j = 0; j < 14; ++j)
                async16(gl + j * 512, rowb + (1 + j * 8) * 64);  // uniform LDS base
        } else {
            #pragma unroll
            for (int t = 0; t < 14; ++t)
                *(uint4*)(rowb + t * 512 + lane * 8) = (uint4){0,0,0,0};
            if (lane < 16) *(uint4*)(rowb + 7168 + lane * 8) = (uint4){0,0,0,0};
        }
    }
    __syncthreads();   // compiler drains vmcnt (global_load_lds) here

    floatx4 acc[7][4];
    #pragma unroll
    for (int mt = 0; mt < 7; ++mt)
        #pragma unroll
        for (int ot = 0; ot < 4; ++ot)
            acc[mt][ot] = (floatx4){0.f, 0.f, 0.f, 0.f};

    const unsigned short* wA = ws16 + WT_OFF_EL;
    const int row_idx = wave >> 1;          // which of the 2 output rows
    const int o0 = (wave & 1) * 64;
    const int aL = (o0 + lane_lo) * 32 + lane_hi * 8;  // lane offset in [128o][32c]

    // A-frags double-buffered across taps (weights are L1/L2-hot)
    short8 a[2][2][4];
    #pragma unroll
    for (int k01 = 0; k01 < 2; ++k01)
        #pragma unroll
        for (int ot = 0; ot < 4; ++ot)
            a[0][k01][ot] = *(const short8*)(wA + k01 * 4096 + ot * 512 + aL);

    #pragma unroll
    for (int tap = 0; tap < 9; ++tap) {
        const int dh = tap / 3 - 1;
        const int dw = tap % 3 - 1;
        const int cur = tap & 1, nxt = cur ^ 1;
        if (tap < 8) {
            #pragma unroll
            for (int k01 = 0; k01 < 2; ++k01)
                #pragma unroll
                for (int ot = 0; ot < 4; ++ot)
                    a[nxt][k01][ot] = *(const short8*)(
                        wA + ((tap + 1) * 2 + k01) * 4096 + ot * 512 + aL);
        }
        const int colL = lane_lo + dw + 1;                 // stored col for mt=0
        const unsigned short* sb = sx + (row_idx + 1 + dh) * ROWE + colL * 64;
        const int sw0 = (lane_hi ^ (colL & 7)) * 8;        // k01=0 swizzle
        const int sw1 = ((lane_hi + 4) ^ (colL & 7)) * 8;  // k01=1 swizzle

        #pragma unroll
        for (int mt = 0; mt < 7; ++mt) {
            const short8 b0 = *(const short8*)(sb + mt * 1024 + sw0);
            const short8 b1 = *(const short8*)(sb + mt * 1024 + sw1);
            #pragma unroll
            for (int ot = 0; ot < 4; ++ot)
                acc[mt][ot] = __builtin_amdgcn_mfma_f32_16x16x32_bf16(
                    a[cur][0][ot], b0, acc[mt][ot], 0, 0, 0);
            #pragma unroll
            for (int ot = 0; ot < 4; ++ot)
                acc[mt][ot] = __builtin_amdgcn_mfma_f32_16x16x32_bf16(
                    a[cur][1][ot], b1, acc[mt][ot], 0, 0, 0);
        }
    }

    // ---- epilogue: D col = m (lane_lo), row = o_rel = lane_hi*4 + i ----
    const int h = h0 + row_idx;
    #pragma unroll
    for (int ot = 0; ot < 4; ++ot) {
        const int ob = o0 + ot * 16 + lane_hi * 4;
        const float4 bv = *(const float4*)(bias + ob);
        #pragma unroll
        for (int mt = 0; mt < 7; ++mt) {
            const int w = mt * 16 + lane_lo;
            float* op = out + ((size_t)(n * OC + ob) * HW + h) * HW + w;
            op[0]        = acc[mt][ot].x + bv.x;
            op[HWHW]     = acc[mt][ot].y + bv.y;
            op[2 * HWHW] = acc[mt][ot].z + bv.z;
            op[3 * HWHW] = acc[mt][ot].w + bv.w;
        }
    }
}

extern "C" void kernel_launch(void* const* d_in, const int* in_sizes, int n_in,
                              void* d_out, int out_size, void* d_ws, size_t ws_size,
                              hipStream_t stream) {
    const float* x    = (const float*)d_in[0];
    const float* wgt  = (const float*)d_in[1];
    const float* bias = (const float*)d_in[2];
    float* out = (float*)d_out;
    unsigned short* ws16 = (unsigned short*)d_ws;

    hipLaunchKernelGGL(xform_x, dim3(NIMG * HW), dim3(256), 0, stream, x, ws16);
    hipLaunchKernelGGL(xform_w, dim3(288), dim3(256), 0, stream, wgt, ws16);
    hipLaunchKernelGGL(conv_mfma, dim3(NIMG * 56), dim3(256), 0, stream,
                       ws16, bias, out);
}